// Round 21
// baseline (81.459 us; speedup 1.0000x reference)
//
#include <hip/hip_runtime.h>
#include <hip/hip_fp16.h>

#define NN 4096
#define SDIM 64
#define HID 128
#define HEADS 4
#define FF 32
#define NSPLIT 8

typedef __attribute__((ext_vector_type(8))) _Float16 h8;      // MFMA f16 A/B frag
typedef __attribute__((ext_vector_type(2))) _Float16 h2;      // packed half2
typedef __attribute__((ext_vector_type(4))) float f32x4;      // MFMA C/D
typedef __attribute__((ext_vector_type(4))) unsigned short us4;

// ---------------- workspace layout (float units) ----------------
// hTf  : 0        (262144 f = 524288 fp16)  fragment-ordered h^T
// s1   : 262144   s2: 278528   (16384 each)
// abit : 294912   (524288 f = 2 MB bits)
// pout : 819200   (2097152 f = 4.2M fp16)   8 splits
// pden : 2916352  (131072)
// total 3047424 floats = 12.2 MB

// ============ K1: grid-partitioned prep (blocks 0..511, 8 rows each, LDS-staged W)
//                  + adjacency bit-pack (blocks 512..4607, 1 row each) ============
// (R15-verified body)
__global__ __launch_bounds__(256) void k_prep_pack(
        const float* __restrict__ state,
        const float* __restrict__ W1, const float* __restrict__ b1,
        const float* __restrict__ W2, const float* __restrict__ b2,
        const float* __restrict__ Wg, const float* __restrict__ ag,
        const int* __restrict__ adj,
        unsigned short* __restrict__ hTf,
        float* __restrict__ s1b, float* __restrict__ s2b,
        unsigned int* __restrict__ abit) {
    int tid = threadIdx.x;

    if (blockIdx.x >= 512) {
        // ---- pack branch: thread t packs 16 ints -> ushort ----
        int r = blockIdx.x - 512;
        const int4* ap = (const int4*)(adj + (size_t)r * NN + tid * 16);
        unsigned int b = 0;
#pragma unroll
        for (int i = 0; i < 4; i++) {
            int4 a = ap[i];
            b |= (unsigned int)(a.x != 0) << (i * 4 + 0);
            b |= (unsigned int)(a.y != 0) << (i * 4 + 1);
            b |= (unsigned int)(a.z != 0) << (i * 4 + 2);
            b |= (unsigned int)(a.w != 0) << (i * 4 + 3);
        }
        ((unsigned short*)abit)[r * 256 + tid] = (unsigned short)b;
        return;
    }

    // ---- prep branch: 8 rows/block, 256 threads, weights staged in LDS ----
    __shared__ float wbuf[8192];      // 32 KB staging (W1 | W2-half | Wg-half)
    __shared__ float srow[8][64];
    __shared__ float x1s[8][128];
    __shared__ float x2s[8][128];
    int r0 = blockIdx.x * 8;
    int c = tid & 127, g = tid >> 7;          // g = row-quad 0..1

    if (tid < 128)
        ((float4*)&srow[0][0])[tid] = ((const float4*)(state + (size_t)r0 * SDIM))[tid];
#pragma unroll
    for (int i = 0; i < 8; i++)
        ((float4*)wbuf)[tid + i * 256] = ((const float4*)W1)[tid + i * 256];
    __syncthreads();

    float acc[4];
    {   // x1 = relu(state@W1+b1), W1 from LDS
        float bb = b1[c];
#pragma unroll
        for (int r = 0; r < 4; r++) acc[r] = bb;
#pragma unroll 8
        for (int k = 0; k < SDIM; k++) {
            float w = wbuf[k * HID + c];
#pragma unroll
            for (int r = 0; r < 4; r++) acc[r] += w * srow[g * 4 + r][k];
        }
#pragma unroll
        for (int r = 0; r < 4; r++) x1s[g * 4 + r][c] = fmaxf(acc[r], 0.f);
    }

    {   // x2 = relu(x1@W2+b2), W2 staged in two 32 KB halves
        float bb = b2[c];
#pragma unroll
        for (int r = 0; r < 4; r++) acc[r] = bb;
#pragma unroll
        for (int hh = 0; hh < 2; hh++) {
            __syncthreads();
#pragma unroll
            for (int i = 0; i < 8; i++)
                ((float4*)wbuf)[tid + i * 256] = ((const float4*)(W2 + hh * 8192))[tid + i * 256];
            __syncthreads();
#pragma unroll 8
            for (int k = 0; k < 64; k++) {
                float w = wbuf[k * HID + c];
#pragma unroll
                for (int r = 0; r < 4; r++) acc[r] += w * x1s[g * 4 + r][hh * 64 + k];
            }
        }
#pragma unroll
        for (int r = 0; r < 4; r++) x2s[g * 4 + r][c] = fmaxf(acc[r], 0.f);
    }

    int hd = c >> 5, f = c & 31;
    float hacc[4];
#pragma unroll
    for (int r = 0; r < 4; r++) hacc[r] = 0.f;
    {   // h = x2 @ Wg, Wg staged in two halves; LDS index k*128 + hd*32 + f
#pragma unroll
        for (int hh = 0; hh < 2; hh++) {
            __syncthreads();
#pragma unroll
            for (int i = 0; i < 32; i++) {
                int L = tid + i * 256;
                int kk = L >> 7, cc = L & 127;
                wbuf[L] = Wg[(cc >> 5) * (HID * FF) + (hh * 64 + kk) * FF + (cc & 31)];
            }
            __syncthreads();
#pragma unroll 8
            for (int k = 0; k < 64; k++) {
                float w = wbuf[k * HID + c];
#pragma unroll
                for (int r = 0; r < 4; r++) hacc[r] += w * x2s[g * 4 + r][hh * 64 + k];
            }
        }
    }

    // h^T frag order (fp16): idx(hd,f,m) =
    //   ((hd*128 + (m>>5))*2 + (f>>4))*512 + (f&15)*32 + ((m&31)>>3)*8 + (m&7)
    {
        int bn = f >> 4, fr = f & 15;
        int m31 = (r0 & 31) + g * 4;
        us4 pk;
#pragma unroll
        for (int r = 0; r < 4; r++) pk[r] = __half_as_ushort(__float2half(hacc[r]));
        *(us4*)(hTf + (size_t)((hd * 128 + (r0 >> 5)) * 2 + bn) * 512
                + fr * 32 + (m31 >> 3) * 8 + (m31 & 7)) = pk;
    }

    float a1v = ag[hd * 64 + f];
    float a2v = ag[hd * 64 + 32 + f];
#pragma unroll
    for (int r = 0; r < 4; r++) {
        float p1 = hacc[r] * a1v;
        float p2 = hacc[r] * a2v;
#pragma unroll
        for (int s = 16; s >= 1; s >>= 1) {
            p1 += __shfl_xor(p1, s, 32);
            p2 += __shfl_xor(p2, s, 32);
        }
        if (f == 0) {
            s1b[hd * NN + r0 + g * 4 + r] = p1;
            s2b[hd * NN + r0 + g * 4 + r] = p2;
        }
    }
}

// ============ K2: attention — inline headprep, packed-f16 w-build, mask LUT ============
// (R15-verified body)
__global__ __launch_bounds__(256, 3) void k_attn(
        const unsigned int* __restrict__ abit, const unsigned short* __restrict__ hTf,
        const float* __restrict__ s1b, const float* __restrict__ s2b,
        __half* __restrict__ pout, float* __restrict__ pden) {
    __shared__ unsigned short hTl[16384];     // 32 KB, [ks*2+bn][lane] lane-linear frags
    __shared__ unsigned int abits[128][17];   // 128 rows x 16 words, padded
    __shared__ unsigned short e2l[512];       // fp16 E2 for this head's m-chunk
    __shared__ unsigned short esl[512];       // fp16 E2s
    __shared__ float redm[4];                 // per-wave s2 maxes
    __shared__ uint2 mlut[16];                // nibble -> two 32-bit half-pair masks

    int tid = threadIdx.x;
    int tile = blockIdx.x & 31;
    int split = (blockIdx.x >> 5) & 7;
    int hd = blockIdx.x >> 8;
    int nb = tile * 128, m0 = split * 512;

    if (tid < 16) {   // build mask LUT
        unsigned int lo = ((tid & 1) ? 0xFFFFu : 0u) | ((tid & 2) ? 0xFFFF0000u : 0u);
        unsigned int hi = ((tid & 4) ? 0xFFFFu : 0u) | ((tid & 8) ? 0xFFFF0000u : 0u);
        mlut[tid] = make_uint2(lo, hi);
    }
    {   // stage hT tile: 2048 frags (uint4), permuted src -> lane-linear LDS
#pragma unroll
        for (int i = 0; i < 8; i++) {
            int li = tid + i * 256;                     // (fb*2+bn)*64 + lane
            int lane2 = li & 63;
            int fr2 = lane2 & 15, mo2 = lane2 >> 4;
            int ksbn = li >> 6;                          // fb*2+bn
            const unsigned short* src = hTf
                + (size_t)((hd * 128 + (m0 >> 5) + (ksbn >> 1)) * 2 + (ksbn & 1)) * 512
                + fr2 * 32 + mo2 * 8;
            *(uint4*)&hTl[li * 8] = *(const uint4*)src;
        }
    }
    {   // stage adjacency: 128 rows x 16 words (2 uint4 per thread)
        int r = tid >> 1, q = (tid & 1) * 8;
        const unsigned int* src = abit + (size_t)(nb + r) * 128 + split * 16 + q;
        *(uint4*)&abits[r][q] = *(const uint4*)src;
        *(uint4*)&abits[r][q + 4] = *(const uint4*)(src + 4);
    }

    // inline headprep part 1: A2 = max over this head's full s2 row
    {
        float m = -1e30f;
        const f32x4* s2p4 = (const f32x4*)(s2b + hd * NN);
#pragma unroll
        for (int i = 0; i < 4; i++) {
            f32x4 v = s2p4[tid + i * 256];
            m = fmaxf(fmaxf(m, fmaxf(v[0], v[1])), fmaxf(v[2], v[3]));
        }
#pragma unroll
        for (int s = 32; s >= 1; s >>= 1) m = fmaxf(m, __shfl_xor(m, s, 64));
        if ((tid & 63) == 0) redm[tid >> 6] = m;
    }
    __syncthreads();
    float A2 = fmaxf(fmaxf(redm[0], redm[1]), fmaxf(redm[2], redm[3]));

    // inline headprep part 2: E2/E2s slices for this m-chunk (fp16, LDS)
#pragma unroll
    for (int i = 0; i < 2; i++) {
        int mm = tid + i * 256;
        float v2 = s2b[hd * NN + m0 + mm];
        e2l[mm] = __half_as_ushort(__float2half(__expf(v2 - A2)));
        esl[mm] = __half_as_ushort(__float2half(__expf(0.2f * (v2 - A2))));
    }

    int w = tid >> 6, lane = tid & 63;
    int fr = lane & 15, mo = lane >> 4;
    int nw0 = nb + w * 32;

    // inline headprep part 3: per-row cp/cn in registers (h2 broadcast)
    h2 cph[2], cnh[2];
#pragma unroll
    for (int am = 0; am < 2; am++) {
        int n = nw0 + am * 16 + fr;
        float v1 = s1b[hd * NN + n];
        float u = v1 + A2;
        float C = fmaxf(u, 0.2f * u);
        _Float16 t1 = (_Float16)__expf(u - C);
        _Float16 t2 = (_Float16)__expf(0.2f * u - C);
        cph[am][0] = t1; cph[am][1] = t1;
        cnh[am][0] = t2; cnh[am][1] = t2;
    }
    __syncthreads();

    f32x4 acc[2][2];
    f32x4 accden[2];
#pragma unroll
    for (int am = 0; am < 2; am++) {
#pragma unroll
        for (int bn = 0; bn < 2; bn++) acc[am][bn] = (f32x4){0.f, 0.f, 0.f, 0.f};
        accden[am] = (f32x4){0.f, 0.f, 0.f, 0.f};
    }

    h8 ones;
#pragma unroll
    for (int j = 0; j < 8; j++) ones[j] = (_Float16)1.0f;

#pragma unroll 2
    for (int ks = 0; ks < 16; ks++) {
        h8 B0 = *(const h8*)&hTl[(ks * 2 + 0) * 512 + lane * 8];
        h8 B1 = *(const h8*)&hTl[(ks * 2 + 1) * 512 + lane * 8];
        const h2* e2p = (const h2*)&e2l[ks * 32 + mo * 8];
        const h2* esp = (const h2*)&esl[ks * 32 + mo * 8];

#pragma unroll
        for (int am = 0; am < 2; am++) {
            unsigned int bits = abits[w * 32 + am * 16 + fr][ks] >> (mo * 8);
            uint2 m01 = mlut[bits & 15];
            uint2 m23 = mlut[(bits >> 4) & 15];
            union { unsigned int u[4]; h8 v; } A;
#pragma unroll
            for (int p = 0; p < 4; p++) {
                h2 w2 = __builtin_elementwise_max(cph[am] * e2p[p], cnh[am] * esp[p]);
                unsigned int wm;
                __builtin_memcpy(&wm, &w2, 4);
                unsigned int mk = (p == 0) ? m01.x : (p == 1) ? m01.y : (p == 2) ? m23.x : m23.y;
                A.u[p] = wm & mk;
            }
            acc[am][0] = __builtin_amdgcn_mfma_f32_16x16x32_f16(A.v, B0, acc[am][0], 0, 0, 0);
            acc[am][1] = __builtin_amdgcn_mfma_f32_16x16x32_f16(A.v, B1, acc[am][1], 0, 0, 0);
            accden[am] = __builtin_amdgcn_mfma_f32_16x16x32_f16(A.v, ones, accden[am], 0, 0, 0);
        }
    }

    __half* pob = pout + ((size_t)(split * 4 + hd) * NN + nw0) * FF;
#pragma unroll
    for (int am = 0; am < 2; am++) {
#pragma unroll
        for (int bn = 0; bn < 2; bn++) {
            f32x4 cv = acc[am][bn];
#pragma unroll
            for (int r = 0; r < 4; r++)
                pob[(am * 16 + mo * 4 + r) * FF + bn * 16 + fr] = __float2half(cv[r]);
        }
        // accden D-layout: row = mo*4+r, col = fr (all cols equal rowsum)
        if (fr == 0) {
#pragma unroll
            for (int r = 0; r < 4; r++)
                pden[(size_t)(split * 4 + hd) * NN + nw0 + am * 16 + mo * 4 + r] = accden[am][r];
        }
    }
}

// ============ K3: fused reduce + policy + value (256 blocks x 512 thr) ============
// (R15-verified body; launched 3x this round as a timing bisect — idempotent)
__global__ __launch_bounds__(512) void k_redpolval(
        const __half* __restrict__ pout, const float* __restrict__ pden,
        const float* __restrict__ Wp1, const float* __restrict__ bp1,
        const float* __restrict__ Wp2, const float* __restrict__ bp2,
        const float* __restrict__ Wv1, const float* __restrict__ bv1,
        const float* __restrict__ Wv2, const float* __restrict__ bv2,
        float* __restrict__ out) {
    __shared__ float fr8[16][128];
    __shared__ float hh[16][128];
    __shared__ float dens[16][4];
    int tid = threadIdx.x;
    int r0 = blockIdx.x * 16;

    // ---- phase 1: den[n][hd] = sum over 8 splits ----
    {
        int p = tid >> 3, sg = tid & 7;     // p = r*4+hd
        int r = p >> 2, hd = p & 3;
        float d = pden[(size_t)(sg * 4 + hd) * NN + r0 + r];
#pragma unroll
        for (int s = 4; s >= 1; s >>= 1) d += __shfl_xor(d, s, 8);
        if (sg == 0) dens[r][hd] = d;
    }

    // ---- phase 2: feat = (sum of fp16 partials) / den ----
    int row = tid >> 5, c4 = (tid & 31) * 4;
    int hd2 = c4 >> 5;
    float o4[4] = {0.f, 0.f, 0.f, 0.f};
    const __half* pp = pout + ((size_t)hd2 * NN + r0 + row) * 32 + (c4 & 31);
#pragma unroll
    for (int s = 0; s < NSPLIT; s++) {
        float2 raw = *(const float2*)(pp + (size_t)s * 4 * NN * 32);
        __half2 ha = *(__half2*)&raw.x;
        __half2 hb = *(__half2*)&raw.y;
        float2 fa = __half22float2(ha), fb = __half22float2(hb);
        o4[0] += fa.x; o4[1] += fa.y; o4[2] += fb.x; o4[3] += fb.y;
    }
    __syncthreads();
    {
        float dn = fmaxf(dens[row][hd2], 1e-30f);
#pragma unroll
        for (int i = 0; i < 4; i++) fr8[row][c4 + i] = o4[i] / dn;
    }
    __syncthreads();

    int c = tid & 127, g = tid >> 7;
    int c2 = tid & 31, r = tid >> 5;

    // ---- phase 3a: policy hidden ----
    {
        float acc[4];
        float bb = bp1[c];
#pragma unroll
        for (int q = 0; q < 4; q++) acc[q] = bb;
#pragma unroll 8
        for (int k = 0; k < HID; k++) {
            float w = Wp1[k * HID + c];
#pragma unroll
            for (int q = 0; q < 4; q++) acc[q] += w * fr8[g * 4 + q][k];
        }
#pragma unroll
        for (int q = 0; q < 4; q++) hh[g * 4 + q][c] = fmaxf(acc[q], 0.f);
    }
    __syncthreads();
    {   // policy out + softmax
        float lacc = bp2[c2];
#pragma unroll 8
        for (int k = 0; k < HID; k++) lacc += hh[r][k] * Wp2[k * 32 + c2];
        float mx = lacc;
#pragma unroll
        for (int s = 16; s >= 1; s >>= 1) mx = fmaxf(mx, __shfl_xor(mx, s, 32));
        float e = __expf(lacc - mx);
        float sm = e;
#pragma unroll
        for (int s = 16; s >= 1; s >>= 1) sm += __shfl_xor(sm, s, 32);
        out[(size_t)(r0 + r) * 32 + c2] = e / sm;
    }
    __syncthreads();

    // ---- phase 3b: value hidden (reuse hh) ----
    {
        float acc[4];
        float bb = bv1[c];
#pragma unroll
        for (int q = 0; q < 4; q++) acc[q] = bb;
#pragma unroll 8
        for (int k = 0; k < HID; k++) {
            float w = Wv1[k * HID + c];
#pragma unroll
            for (int q = 0; q < 4; q++) acc[q] += w * fr8[g * 4 + q][k];
        }
#pragma unroll
        for (int q = 0; q < 4; q++) hh[g * 4 + q][c] = fmaxf(acc[q], 0.f);
    }
    __syncthreads();
    {   // value out
        float p = 0.f;
#pragma unroll
        for (int j = 0; j < 4; j++) p += hh[r][c2 + j * 32] * Wv2[c2 + j * 32];
#pragma unroll
        for (int s = 16; s >= 1; s >>= 1) p += __shfl_xor(p, s, 32);
        if (c2 == 0) out[131072 + r0 + r] = p + bv2[0];
    }
}

extern "C" void kernel_launch(void* const* d_in, const int* in_sizes, int n_in,
                              void* d_out, int out_size, void* d_ws, size_t ws_size,
                              hipStream_t stream) {
    const float* state = (const float*)d_in[0];
    const int*   adj   = (const int*)d_in[1];
    const float* W1  = (const float*)d_in[2];
    const float* b1  = (const float*)d_in[3];
    const float* W2  = (const float*)d_in[4];
    const float* b2  = (const float*)d_in[5];
    const float* Wg  = (const float*)d_in[6];
    const float* ag  = (const float*)d_in[7];
    const float* Wp1 = (const float*)d_in[8];
    const float* bp1 = (const float*)d_in[9];
    const float* Wp2 = (const float*)d_in[10];
    const float* bp2 = (const float*)d_in[11];
    const float* Wv1 = (const float*)d_in[12];
    const float* bv1 = (const float*)d_in[13];
    const float* Wv2 = (const float*)d_in[14];
    const float* bv2 = (const float*)d_in[15];
    float* out = (float*)d_out;
    float* ws = (float*)d_ws;

    unsigned short* hTf = (unsigned short*)ws;            // 524288 fp16
    float* s1b  = ws + 262144;
    float* s2b  = ws + 278528;
    unsigned int* abit = (unsigned int*)(ws + 294912);    // 2 MB
    __half* pout = (__half*)(ws + 819200);                // 4.2M fp16
    float* pden = ws + 2916352;

    hipLaunchKernelGGL(k_prep_pack, dim3(512 + NN), dim3(256), 0, stream,
                       state, W1, b1, W2, b2, Wg, ag, adj, hTf, s1b, s2b, abit);
    hipLaunchKernelGGL(k_attn, dim3(32 * NSPLIT * HEADS), dim3(256), 0, stream,
                       abit, hTf, s1b, s2b, pout, pden);
    // BISECT: launch k_redpolval 3x (idempotent rewrite of out from unchanged pout/pden).
    // dur - 54.8 = 2 x (redpolval + boundary overhead).
    hipLaunchKernelGGL(k_redpolval, dim3(NN / 16), dim3(512), 0, stream,
                       pout, pden, Wp1, bp1, Wp2, bp2, Wv1, bv1, Wv2, bv2, out);
    hipLaunchKernelGGL(k_redpolval, dim3(NN / 16), dim3(512), 0, stream,
                       pout, pden, Wp1, bp1, Wp2, bp2, Wv1, bv1, Wv2, bv2, out);
    hipLaunchKernelGGL(k_redpolval, dim3(NN / 16), dim3(512), 0, stream,
                       pout, pden, Wp1, bp1, Wp2, bp2, Wv1, bv1, Wv2, bv2, out);
}

// Round 22
// 49.144 us; speedup vs baseline: 1.6576x; 1.6576x over previous
//
#include <hip/hip_runtime.h>
#include <hip/hip_fp16.h>

#define NN 4096
#define SDIM 64
#define HID 128
#define HEADS 4
#define FF 32
#define NSPLIT 8

typedef __attribute__((ext_vector_type(8))) _Float16 h8;      // MFMA f16 A/B frag
typedef __attribute__((ext_vector_type(2))) _Float16 h2;      // packed half2
typedef __attribute__((ext_vector_type(4))) float f32x4;      // MFMA C/D
typedef __attribute__((ext_vector_type(4))) unsigned short us4;

// ---------------- workspace layout (float units) ----------------
// hTf  : 0        (262144 f = 524288 fp16)  fragment-ordered h^T
// s1   : 262144   s2: 278528   (16384 each)
// abit : 294912   (524288 f = 2 MB bits)
// pout : 819200   (2097152 f = 4.2M fp16)   8 splits
// pden : 2916352  (131072)
// total 3047424 floats = 12.2 MB

// ============ K1: grid-partitioned prep (blocks 0..511, 8 rows each, LDS-staged W)
//                  + adjacency bit-pack (blocks 512..4607, 1 row each) ============
// (R15-verified body)
__global__ __launch_bounds__(256) void k_prep_pack(
        const float* __restrict__ state,
        const float* __restrict__ W1, const float* __restrict__ b1,
        const float* __restrict__ W2, const float* __restrict__ b2,
        const float* __restrict__ Wg, const float* __restrict__ ag,
        const int* __restrict__ adj,
        unsigned short* __restrict__ hTf,
        float* __restrict__ s1b, float* __restrict__ s2b,
        unsigned int* __restrict__ abit) {
    int tid = threadIdx.x;

    if (blockIdx.x >= 512) {
        // ---- pack branch: thread t packs 16 ints -> ushort ----
        int r = blockIdx.x - 512;
        const int4* ap = (const int4*)(adj + (size_t)r * NN + tid * 16);
        unsigned int b = 0;
#pragma unroll
        for (int i = 0; i < 4; i++) {
            int4 a = ap[i];
            b |= (unsigned int)(a.x != 0) << (i * 4 + 0);
            b |= (unsigned int)(a.y != 0) << (i * 4 + 1);
            b |= (unsigned int)(a.z != 0) << (i * 4 + 2);
            b |= (unsigned int)(a.w != 0) << (i * 4 + 3);
        }
        ((unsigned short*)abit)[r * 256 + tid] = (unsigned short)b;
        return;
    }

    // ---- prep branch: 8 rows/block, 256 threads, weights staged in LDS ----
    __shared__ float wbuf[8192];      // 32 KB staging (W1 | W2-half | Wg-half)
    __shared__ float srow[8][64];
    __shared__ float x1s[8][128];
    __shared__ float x2s[8][128];
    int r0 = blockIdx.x * 8;
    int c = tid & 127, g = tid >> 7;          // g = row-quad 0..1

    if (tid < 128)
        ((float4*)&srow[0][0])[tid] = ((const float4*)(state + (size_t)r0 * SDIM))[tid];
#pragma unroll
    for (int i = 0; i < 8; i++)
        ((float4*)wbuf)[tid + i * 256] = ((const float4*)W1)[tid + i * 256];
    __syncthreads();

    float acc[4];
    {   // x1 = relu(state@W1+b1), W1 from LDS
        float bb = b1[c];
#pragma unroll
        for (int r = 0; r < 4; r++) acc[r] = bb;
#pragma unroll 8
        for (int k = 0; k < SDIM; k++) {
            float w = wbuf[k * HID + c];
#pragma unroll
            for (int r = 0; r < 4; r++) acc[r] += w * srow[g * 4 + r][k];
        }
#pragma unroll
        for (int r = 0; r < 4; r++) x1s[g * 4 + r][c] = fmaxf(acc[r], 0.f);
    }

    {   // x2 = relu(x1@W2+b2), W2 staged in two 32 KB halves
        float bb = b2[c];
#pragma unroll
        for (int r = 0; r < 4; r++) acc[r] = bb;
#pragma unroll
        for (int hh = 0; hh < 2; hh++) {
            __syncthreads();
#pragma unroll
            for (int i = 0; i < 8; i++)
                ((float4*)wbuf)[tid + i * 256] = ((const float4*)(W2 + hh * 8192))[tid + i * 256];
            __syncthreads();
#pragma unroll 8
            for (int k = 0; k < 64; k++) {
                float w = wbuf[k * HID + c];
#pragma unroll
                for (int r = 0; r < 4; r++) acc[r] += w * x1s[g * 4 + r][hh * 64 + k];
            }
        }
#pragma unroll
        for (int r = 0; r < 4; r++) x2s[g * 4 + r][c] = fmaxf(acc[r], 0.f);
    }

    int hd = c >> 5, f = c & 31;
    float hacc[4];
#pragma unroll
    for (int r = 0; r < 4; r++) hacc[r] = 0.f;
    {   // h = x2 @ Wg, Wg staged in two halves; LDS index k*128 + hd*32 + f
#pragma unroll
        for (int hh = 0; hh < 2; hh++) {
            __syncthreads();
#pragma unroll
            for (int i = 0; i < 32; i++) {
                int L = tid + i * 256;
                int kk = L >> 7, cc = L & 127;
                wbuf[L] = Wg[(cc >> 5) * (HID * FF) + (hh * 64 + kk) * FF + (cc & 31)];
            }
            __syncthreads();
#pragma unroll 8
            for (int k = 0; k < 64; k++) {
                float w = wbuf[k * HID + c];
#pragma unroll
                for (int r = 0; r < 4; r++) hacc[r] += w * x2s[g * 4 + r][hh * 64 + k];
            }
        }
    }

    // h^T frag order (fp16): idx(hd,f,m) =
    //   ((hd*128 + (m>>5))*2 + (f>>4))*512 + (f&15)*32 + ((m&31)>>3)*8 + (m&7)
    {
        int bn = f >> 4, fr = f & 15;
        int m31 = (r0 & 31) + g * 4;
        us4 pk;
#pragma unroll
        for (int r = 0; r < 4; r++) pk[r] = __half_as_ushort(__float2half(hacc[r]));
        *(us4*)(hTf + (size_t)((hd * 128 + (r0 >> 5)) * 2 + bn) * 512
                + fr * 32 + (m31 >> 3) * 8 + (m31 & 7)) = pk;
    }

    float a1v = ag[hd * 64 + f];
    float a2v = ag[hd * 64 + 32 + f];
#pragma unroll
    for (int r = 0; r < 4; r++) {
        float p1 = hacc[r] * a1v;
        float p2 = hacc[r] * a2v;
#pragma unroll
        for (int s = 16; s >= 1; s >>= 1) {
            p1 += __shfl_xor(p1, s, 32);
            p2 += __shfl_xor(p2, s, 32);
        }
        if (f == 0) {
            s1b[hd * NN + r0 + g * 4 + r] = p1;
            s2b[hd * NN + r0 + g * 4 + r] = p2;
        }
    }
}

// ============ K2: attention — inline headprep, packed-f16 w-build, mask LUT ============
// (R15-verified body)
__global__ __launch_bounds__(256, 3) void k_attn(
        const unsigned int* __restrict__ abit, const unsigned short* __restrict__ hTf,
        const float* __restrict__ s1b, const float* __restrict__ s2b,
        __half* __restrict__ pout, float* __restrict__ pden) {
    __shared__ unsigned short hTl[16384];     // 32 KB, [ks*2+bn][lane] lane-linear frags
    __shared__ unsigned int abits[128][17];   // 128 rows x 16 words, padded
    __shared__ unsigned short e2l[512];       // fp16 E2 for this head's m-chunk
    __shared__ unsigned short esl[512];       // fp16 E2s
    __shared__ float redm[4];                 // per-wave s2 maxes
    __shared__ uint2 mlut[16];                // nibble -> two 32-bit half-pair masks

    int tid = threadIdx.x;
    int tile = blockIdx.x & 31;
    int split = (blockIdx.x >> 5) & 7;
    int hd = blockIdx.x >> 8;
    int nb = tile * 128, m0 = split * 512;

    if (tid < 16) {   // build mask LUT
        unsigned int lo = ((tid & 1) ? 0xFFFFu : 0u) | ((tid & 2) ? 0xFFFF0000u : 0u);
        unsigned int hi = ((tid & 4) ? 0xFFFFu : 0u) | ((tid & 8) ? 0xFFFF0000u : 0u);
        mlut[tid] = make_uint2(lo, hi);
    }
    {   // stage hT tile: 2048 frags (uint4), permuted src -> lane-linear LDS
#pragma unroll
        for (int i = 0; i < 8; i++) {
            int li = tid + i * 256;                     // (fb*2+bn)*64 + lane
            int lane2 = li & 63;
            int fr2 = lane2 & 15, mo2 = lane2 >> 4;
            int ksbn = li >> 6;                          // fb*2+bn
            const unsigned short* src = hTf
                + (size_t)((hd * 128 + (m0 >> 5) + (ksbn >> 1)) * 2 + (ksbn & 1)) * 512
                + fr2 * 32 + mo2 * 8;
            *(uint4*)&hTl[li * 8] = *(const uint4*)src;
        }
    }
    {   // stage adjacency: 128 rows x 16 words (2 uint4 per thread)
        int r = tid >> 1, q = (tid & 1) * 8;
        const unsigned int* src = abit + (size_t)(nb + r) * 128 + split * 16 + q;
        *(uint4*)&abits[r][q] = *(const uint4*)src;
        *(uint4*)&abits[r][q + 4] = *(const uint4*)(src + 4);
    }

    // inline headprep part 1: A2 = max over this head's full s2 row
    {
        float m = -1e30f;
        const f32x4* s2p4 = (const f32x4*)(s2b + hd * NN);
#pragma unroll
        for (int i = 0; i < 4; i++) {
            f32x4 v = s2p4[tid + i * 256];
            m = fmaxf(fmaxf(m, fmaxf(v[0], v[1])), fmaxf(v[2], v[3]));
        }
#pragma unroll
        for (int s = 32; s >= 1; s >>= 1) m = fmaxf(m, __shfl_xor(m, s, 64));
        if ((tid & 63) == 0) redm[tid >> 6] = m;
    }
    __syncthreads();
    float A2 = fmaxf(fmaxf(redm[0], redm[1]), fmaxf(redm[2], redm[3]));

    // inline headprep part 2: E2/E2s slices for this m-chunk (fp16, LDS)
#pragma unroll
    for (int i = 0; i < 2; i++) {
        int mm = tid + i * 256;
        float v2 = s2b[hd * NN + m0 + mm];
        e2l[mm] = __half_as_ushort(__float2half(__expf(v2 - A2)));
        esl[mm] = __half_as_ushort(__float2half(__expf(0.2f * (v2 - A2))));
    }

    int w = tid >> 6, lane = tid & 63;
    int fr = lane & 15, mo = lane >> 4;
    int nw0 = nb + w * 32;

    // inline headprep part 3: per-row cp/cn in registers (h2 broadcast)
    h2 cph[2], cnh[2];
#pragma unroll
    for (int am = 0; am < 2; am++) {
        int n = nw0 + am * 16 + fr;
        float v1 = s1b[hd * NN + n];
        float u = v1 + A2;
        float C = fmaxf(u, 0.2f * u);
        _Float16 t1 = (_Float16)__expf(u - C);
        _Float16 t2 = (_Float16)__expf(0.2f * u - C);
        cph[am][0] = t1; cph[am][1] = t1;
        cnh[am][0] = t2; cnh[am][1] = t2;
    }
    __syncthreads();

    f32x4 acc[2][2];
    f32x4 accden[2];
#pragma unroll
    for (int am = 0; am < 2; am++) {
#pragma unroll
        for (int bn = 0; bn < 2; bn++) acc[am][bn] = (f32x4){0.f, 0.f, 0.f, 0.f};
        accden[am] = (f32x4){0.f, 0.f, 0.f, 0.f};
    }

    h8 ones;
#pragma unroll
    for (int j = 0; j < 8; j++) ones[j] = (_Float16)1.0f;

#pragma unroll 2
    for (int ks = 0; ks < 16; ks++) {
        h8 B0 = *(const h8*)&hTl[(ks * 2 + 0) * 512 + lane * 8];
        h8 B1 = *(const h8*)&hTl[(ks * 2 + 1) * 512 + lane * 8];
        const h2* e2p = (const h2*)&e2l[ks * 32 + mo * 8];
        const h2* esp = (const h2*)&esl[ks * 32 + mo * 8];

#pragma unroll
        for (int am = 0; am < 2; am++) {
            unsigned int bits = abits[w * 32 + am * 16 + fr][ks] >> (mo * 8);
            uint2 m01 = mlut[bits & 15];
            uint2 m23 = mlut[(bits >> 4) & 15];
            union { unsigned int u[4]; h8 v; } A;
#pragma unroll
            for (int p = 0; p < 4; p++) {
                h2 w2 = __builtin_elementwise_max(cph[am] * e2p[p], cnh[am] * esp[p]);
                unsigned int wm;
                __builtin_memcpy(&wm, &w2, 4);
                unsigned int mk = (p == 0) ? m01.x : (p == 1) ? m01.y : (p == 2) ? m23.x : m23.y;
                A.u[p] = wm & mk;
            }
            acc[am][0] = __builtin_amdgcn_mfma_f32_16x16x32_f16(A.v, B0, acc[am][0], 0, 0, 0);
            acc[am][1] = __builtin_amdgcn_mfma_f32_16x16x32_f16(A.v, B1, acc[am][1], 0, 0, 0);
            accden[am] = __builtin_amdgcn_mfma_f32_16x16x32_f16(A.v, ones, accden[am], 0, 0, 0);
        }
    }

    __half* pob = pout + ((size_t)(split * 4 + hd) * NN + nw0) * FF;
#pragma unroll
    for (int am = 0; am < 2; am++) {
#pragma unroll
        for (int bn = 0; bn < 2; bn++) {
            f32x4 cv = acc[am][bn];
#pragma unroll
            for (int r = 0; r < 4; r++)
                pob[(am * 16 + mo * 4 + r) * FF + bn * 16 + fr] = __float2half(cv[r]);
        }
        // accden D-layout: row = mo*4+r, col = fr (all cols equal rowsum)
        if (fr == 0) {
#pragma unroll
            for (int r = 0; r < 4; r++)
                pden[(size_t)(split * 4 + hd) * NN + nw0 + am * 16 + mo * 4 + r] = accden[am][r];
        }
    }
}

// ============ K3: grid-split reduce + {policy | value} ============
// 512 blocks x 512 thr, 16 rows each; blocks 0..255 policy, 256..511 value.
// Phase 1+2 duplicated per pair; GEMM phases run at 2 blocks/CU = 4 waves/SIMD.
__global__ __launch_bounds__(512) void k_redpolval(
        const __half* __restrict__ pout, const float* __restrict__ pden,
        const float* __restrict__ Wp1, const float* __restrict__ bp1,
        const float* __restrict__ Wp2, const float* __restrict__ bp2,
        const float* __restrict__ Wv1, const float* __restrict__ bv1,
        const float* __restrict__ Wv2, const float* __restrict__ bv2,
        float* __restrict__ out) {
    __shared__ float fr8[16][128];
    __shared__ float hh[16][128];
    __shared__ float dens[16][4];
    int tid = threadIdx.x;
    bool is_val = blockIdx.x >= 256;
    int r0 = (is_val ? blockIdx.x - 256 : blockIdx.x) * 16;

    // ---- phase 1: den[n][hd] = sum over 8 splits ----
    {
        int p = tid >> 3, sg = tid & 7;     // p = r*4+hd
        int r = p >> 2, hd = p & 3;
        float d = pden[(size_t)(sg * 4 + hd) * NN + r0 + r];
#pragma unroll
        for (int s = 4; s >= 1; s >>= 1) d += __shfl_xor(d, s, 8);
        if (sg == 0) dens[r][hd] = d;
    }

    // ---- phase 2: feat = (sum of fp16 partials) / den ----
    int row = tid >> 5, c4 = (tid & 31) * 4;
    int hd2 = c4 >> 5;
    float o4[4] = {0.f, 0.f, 0.f, 0.f};
    const __half* pp = pout + ((size_t)hd2 * NN + r0 + row) * 32 + (c4 & 31);
#pragma unroll
    for (int s = 0; s < NSPLIT; s++) {
        float2 raw = *(const float2*)(pp + (size_t)s * 4 * NN * 32);
        __half2 ha = *(__half2*)&raw.x;
        __half2 hb = *(__half2*)&raw.y;
        float2 fa = __half22float2(ha), fb = __half22float2(hb);
        o4[0] += fa.x; o4[1] += fa.y; o4[2] += fb.x; o4[3] += fb.y;
    }
    __syncthreads();
    {
        float dn = fmaxf(dens[row][hd2], 1e-30f);
#pragma unroll
        for (int i = 0; i < 4; i++) fr8[row][c4 + i] = o4[i] / dn;
    }
    __syncthreads();

    int c = tid & 127, g = tid >> 7;
    int c2 = tid & 31, r = tid >> 5;

    if (!is_val) {
        // ---- policy hidden ----
        {
            float acc[4];
            float bb = bp1[c];
#pragma unroll
            for (int q = 0; q < 4; q++) acc[q] = bb;
#pragma unroll 8
            for (int k = 0; k < HID; k++) {
                float w = Wp1[k * HID + c];
#pragma unroll
                for (int q = 0; q < 4; q++) acc[q] += w * fr8[g * 4 + q][k];
            }
#pragma unroll
            for (int q = 0; q < 4; q++) hh[g * 4 + q][c] = fmaxf(acc[q], 0.f);
        }
        __syncthreads();
        {   // policy out + softmax
            float lacc = bp2[c2];
#pragma unroll 8
            for (int k = 0; k < HID; k++) lacc += hh[r][k] * Wp2[k * 32 + c2];
            float mx = lacc;
#pragma unroll
            for (int s = 16; s >= 1; s >>= 1) mx = fmaxf(mx, __shfl_xor(mx, s, 32));
            float e = __expf(lacc - mx);
            float sm = e;
#pragma unroll
            for (int s = 16; s >= 1; s >>= 1) sm += __shfl_xor(sm, s, 32);
            out[(size_t)(r0 + r) * 32 + c2] = e / sm;
        }
    } else {
        // ---- value hidden ----
        {
            float acc[4];
            float bb = bv1[c];
#pragma unroll
            for (int q = 0; q < 4; q++) acc[q] = bb;
#pragma unroll 8
            for (int k = 0; k < HID; k++) {
                float w = Wv1[k * HID + c];
#pragma unroll
                for (int q = 0; q < 4; q++) acc[q] += w * fr8[g * 4 + q][k];
            }
#pragma unroll
            for (int q = 0; q < 4; q++) hh[g * 4 + q][c] = fmaxf(acc[q], 0.f);
        }
        __syncthreads();
        {   // value out
            float p = 0.f;
#pragma unroll
            for (int j = 0; j < 4; j++) p += hh[r][c2 + j * 32] * Wv2[c2 + j * 32];
#pragma unroll
            for (int s = 16; s >= 1; s >>= 1) p += __shfl_xor(p, s, 32);
            if (c2 == 0) out[131072 + r0 + r] = p + bv2[0];
        }
    }
}

extern "C" void kernel_launch(void* const* d_in, const int* in_sizes, int n_in,
                              void* d_out, int out_size, void* d_ws, size_t ws_size,
                              hipStream_t stream) {
    const float* state = (const float*)d_in[0];
    const int*   adj   = (const int*)d_in[1];
    const float* W1  = (const float*)d_in[2];
    const float* b1  = (const float*)d_in[3];
    const float* W2  = (const float*)d_in[4];
    const float* b2  = (const float*)d_in[5];
    const float* Wg  = (const float*)d_in[6];
    const float* ag  = (const float*)d_in[7];
    const float* Wp1 = (const float*)d_in[8];
    const float* bp1 = (const float*)d_in[9];
    const float* Wp2 = (const float*)d_in[10];
    const float* bp2 = (const float*)d_in[11];
    const float* Wv1 = (const float*)d_in[12];
    const float* bv1 = (const float*)d_in[13];
    const float* Wv2 = (const float*)d_in[14];
    const float* bv2 = (const float*)d_in[15];
    float* out = (float*)d_out;
    float* ws = (float*)d_ws;

    unsigned short* hTf = (unsigned short*)ws;            // 524288 fp16
    float* s1b  = ws + 262144;
    float* s2b  = ws + 278528;
    unsigned int* abit = (unsigned int*)(ws + 294912);    // 2 MB
    __half* pout = (__half*)(ws + 819200);                // 4.2M fp16
    float* pden = ws + 2916352;

    hipLaunchKernelGGL(k_prep_pack, dim3(512 + NN), dim3(256), 0, stream,
                       state, W1, b1, W2, b2, Wg, ag, adj, hTf, s1b, s2b, abit);
    hipLaunchKernelGGL(k_attn, dim3(32 * NSPLIT * HEADS), dim3(256), 0, stream,
                       abit, hTf, s1b, s2b, pout, pden);
    hipLaunchKernelGGL(k_redpolval, dim3(512), dim3(512), 0, stream,
                       pout, pden, Wp1, bp1, Wp2, bp2, Wv1, bv1, Wv2, bv2, out);
}